// Round 1
// baseline (428.421 us; speedup 1.0000x reference)
//
#include <hip/hip_runtime.h>

#define DIM   128
#define N_REL 500
#define GAMMA 12.0f
#define EPS   1e-12f

// Block = 128 threads (2 waves). Reduce v across the block.
// s2 must be a 2-element LDS scratch. Two syncthreads guard reuse.
__device__ __forceinline__ float blockSum128(float v, float* s2) {
#pragma unroll
    for (int off = 32; off > 0; off >>= 1)
        v += __shfl_xor(v, off, 64);
    const int w = threadIdx.x >> 6;
    __syncthreads();                       // protect s2 from previous call's readers
    if ((threadIdx.x & 63) == 0) s2[w] = v;
    __syncthreads();
    return s2[0] + s2[1];
}

__global__ __launch_bounds__(128) void transr_kernel(
    const int* __restrict__ h, const int* __restrict__ r, const int* __restrict__ t,
    const float* __restrict__ ent_w, const float* __restrict__ rel_w,
    const float* __restrict__ mat_w, float* __restrict__ out)
{
    const int b   = blockIdx.x;
    const int tid = threadIdx.x;           // 0..127, also the element index e

    __shared__ float sh[DIM];              // normalized hv
    __shared__ float st[DIM];              // normalized tv
    __shared__ float s_red[2];
    __shared__ float s_hp[4][DIM];
    __shared__ float s_tp[4][DIM];

    const int   hi   = h[b];
    const int   ti   = t[b];
    const int   ri   = r[b];
    const int   mi   = (ri >= N_REL) ? (ri - N_REL) : ri;   // matrix index (tables doubled)
    const float sign = (ri >= N_REL) ? -1.0f : 1.0f;        // rel_full = [rel; -rel]

    // ---- load raw rows (coalesced: lane e reads element e of a contiguous 512B row)
    float hv = ent_w[(size_t)hi * DIM + tid];
    float tv = ent_w[(size_t)ti * DIM + tid];
    float rv = rel_w[(size_t)mi * DIM + tid];

    // ---- L2 normalize (x / max(||x||, eps))
    const float hs = blockSum128(hv * hv, s_red);
    const float ts = blockSum128(tv * tv, s_red);
    const float rs = blockSum128(rv * rv, s_red);
    hv *= 1.0f / fmaxf(sqrtf(hs), EPS);
    tv *= 1.0f / fmaxf(sqrtf(ts), EPS);
    rv *= sign / fmaxf(sqrtf(rs), EPS);    // note: l2norm(-x) = -l2norm(x)

    sh[tid] = hv;
    st[tid] = tv;
    __syncthreads();

    // ---- mat-vec: hp[e] = sum_d hv[d]*M[d][e]; tp likewise (one matrix read for both)
    // 128 threads = 32 column-groups (float4 of columns) x 4 d-chunks of 32.
    const int cg = tid & 31;               // columns 4*cg .. 4*cg+3
    const int q  = tid >> 5;               // d-chunk 0..3
    const float4* __restrict__ M4 =
        (const float4*)(mat_w + (size_t)mi * DIM * DIM);

    float4 hp4 = make_float4(0.f, 0.f, 0.f, 0.f);
    float4 tp4 = make_float4(0.f, 0.f, 0.f, 0.f);
    const int d0 = 32 * q;
#pragma unroll 8
    for (int dd = 0; dd < 32; ++dd) {
        const int d = d0 + dd;
        const float  a = sh[d];            // LDS broadcast (conflict-free)
        const float  c = st[d];
        const float4 m = M4[d * 32 + cg];  // 16B/lane, wave covers 2 contiguous rows
        hp4.x += a * m.x; hp4.y += a * m.y; hp4.z += a * m.z; hp4.w += a * m.w;
        tp4.x += c * m.x; tp4.y += c * m.y; tp4.z += c * m.z; tp4.w += c * m.w;
    }
    s_hp[q][4 * cg + 0] = hp4.x; s_hp[q][4 * cg + 1] = hp4.y;
    s_hp[q][4 * cg + 2] = hp4.z; s_hp[q][4 * cg + 3] = hp4.w;
    s_tp[q][4 * cg + 0] = tp4.x; s_tp[q][4 * cg + 1] = tp4.y;
    s_tp[q][4 * cg + 2] = tp4.z; s_tp[q][4 * cg + 3] = tp4.w;
    __syncthreads();

    float hp = s_hp[0][tid] + s_hp[1][tid] + s_hp[2][tid] + s_hp[3][tid];
    float tp = s_tp[0][tid] + s_tp[1][tid] + s_tp[2][tid] + s_tp[3][tid];

    // ---- normalize projections, distance, score
    const float hps = blockSum128(hp * hp, s_red);
    const float tps = blockSum128(tp * tp, s_red);
    hp *= 1.0f / fmaxf(sqrtf(hps), EPS);
    tp *= 1.0f / fmaxf(sqrtf(tps), EPS);

    const float dist = hp + rv - tp;
    const float ds   = blockSum128(dist * dist, s_red);
    if (tid == 0) out[b] = GAMMA - sqrtf(ds);
}

extern "C" void kernel_launch(void* const* d_in, const int* in_sizes, int n_in,
                              void* d_out, int out_size, void* d_ws, size_t ws_size,
                              hipStream_t stream) {
    const int*   h     = (const int*)d_in[0];
    const int*   r     = (const int*)d_in[1];
    const int*   t     = (const int*)d_in[2];
    const float* ent_w = (const float*)d_in[3];
    const float* rel_w = (const float*)d_in[4];
    const float* mat_w = (const float*)d_in[5];
    float*       out   = (float*)d_out;
    const int B = in_sizes[0];   // 16384

    transr_kernel<<<B, 128, 0, stream>>>(h, r, t, ent_w, rel_w, mat_w, out);
}

// Round 2
// 367.584 us; speedup vs baseline: 1.1655x; 1.1655x over previous
//
#include <hip/hip_runtime.h>

#define DIM   128
#define N_REL 500
#define GAMMA 12.0f
#define EPS   1e-12f

// ---------------- bucketing ----------------

__global__ void k_zero(int* __restrict__ counts) {
    counts[threadIdx.x] = 0;            // 512 threads
}

__global__ void k_hist(const int* __restrict__ r, int* __restrict__ counts, int B) {
    int i = blockIdx.x * 256 + threadIdx.x;
    if (i < B) {
        int ri = r[i];
        int mi = (ri >= N_REL) ? ri - N_REL : ri;
        atomicAdd(&counts[mi], 1);
    }
}

// 512-wide Hillis-Steele scan; writes exclusive offsets + a mutable cursor copy.
__global__ void k_scan(const int* __restrict__ counts,
                       int* __restrict__ offsets, int* __restrict__ cursor) {
    __shared__ int s[512];
    int tid = threadIdx.x;
    int v = counts[tid];
    s[tid] = v;
    __syncthreads();
    for (int off = 1; off < 512; off <<= 1) {
        int x = (tid >= off) ? s[tid - off] : 0;
        __syncthreads();
        s[tid] += x;
        __syncthreads();
    }
    int excl = s[tid] - v;
    offsets[tid] = excl;
    cursor[tid]  = excl;
}

__global__ void k_scatter(const int* __restrict__ r, int* __restrict__ cursor,
                          int* __restrict__ order, int B) {
    int i = blockIdx.x * 256 + threadIdx.x;
    if (i < B) {
        int ri = r[i];
        int mi = (ri >= N_REL) ? ri - N_REL : ri;
        int pos = atomicAdd(&cursor[mi], 1);
        order[pos] = i;
    }
}

// ---------------- matvec: one block per relation, M register-resident ----------------
// Thread layout: eg = tid&31 (columns 4eg..4eg+3), dc = tid>>5 (d-chunk of 16).
// Skips entity pre-normalization: l2norm(l2norm(x)@M) == l2norm(x@M).

__global__ __launch_bounds__(256) void k_matvec(
    const int* __restrict__ order, const int* __restrict__ offsets,
    const int* __restrict__ counts,
    const int* __restrict__ h, const int* __restrict__ t,
    const float* __restrict__ ent_w, const float* __restrict__ mat_w,
    float* __restrict__ hp_raw, float* __restrict__ tp_raw)
{
    const int rel = blockIdx.x;
    const int cnt_all = counts[rel];
    if (cnt_all == 0) return;
    const int start0 = offsets[rel];
    const int tid = threadIdx.x;
    const int eg = tid & 31;
    const int dc = tid >> 5;
    const int e128 = tid & 127;          // element index for row load / store halves

    const float4* __restrict__ M4 = (const float4*)(mat_w + (size_t)rel * DIM * DIM);
    float4 Mreg[16];
#pragma unroll
    for (int dd = 0; dd < 16; ++dd)
        Mreg[dd] = M4[(dc * 16 + dd) * 32 + eg];

    __shared__ float sv[2][2][DIM];      // [buf][h/t][d] raw entity rows
    __shared__ float part[2][8][DIM];    // [h/t][dc][e] partial sums
    __shared__ int   sb[128], shi[128], sti[128];

    for (int chunk = 0; chunk < cnt_all; chunk += 128) {
        const int cc = min(128, cnt_all - chunk);

        if (tid < cc) {
            int b = order[start0 + chunk + tid];
            sb[tid]  = b;
            shi[tid] = h[b];
            sti[tid] = t[b];
        }
        __syncthreads();

        // preload sample 0 rows
        {
            int row = (tid < 128) ? shi[0] : sti[0];
            sv[0][tid >> 7][e128] = ent_w[(size_t)row * DIM + e128];
        }
        __syncthreads();

        for (int s = 0; s < cc; ++s) {
            const int cur = s & 1, nxt = cur ^ 1;

            // prefetch next sample's rows into registers (non-blocking)
            float pre = 0.0f;
            if (s + 1 < cc) {
                int row = (tid < 128) ? shi[s + 1] : sti[s + 1];
                pre = ent_w[(size_t)row * DIM + e128];
            }

            // compute partial matvec from LDS-broadcast rows + register M
            float4 ah = make_float4(0.f, 0.f, 0.f, 0.f);
            float4 at = make_float4(0.f, 0.f, 0.f, 0.f);
#pragma unroll
            for (int dd = 0; dd < 16; ++dd) {
                const float  a = sv[cur][0][dc * 16 + dd];
                const float  c = sv[cur][1][dc * 16 + dd];
                const float4 m = Mreg[dd];
                ah.x += a * m.x; ah.y += a * m.y; ah.z += a * m.z; ah.w += a * m.w;
                at.x += c * m.x; at.y += c * m.y; at.z += c * m.z; at.w += c * m.w;
            }
            *(float4*)&part[0][dc][4 * eg] = ah;
            *(float4*)&part[1][dc][4 * eg] = at;
            __syncthreads();

            // reduce over the 8 d-chunks and store raw projections
            {
                const int b = sb[s];
                float v = 0.f;
                const int half = tid >> 7;   // 0: hp, 1: tp
#pragma unroll
                for (int k = 0; k < 8; ++k) v += part[half][k][e128];
                float* dst = half ? tp_raw : hp_raw;
                dst[(size_t)b * DIM + e128] = v;
            }

            // stash prefetched rows
            if (s + 1 < cc)
                sv[nxt][tid >> 7][e128] = pre;
            __syncthreads();
        }
    }
}

// ---------------- score: one wave per sample, shuffle-only reductions ----------------

__device__ __forceinline__ float waveSum(float v) {
#pragma unroll
    for (int off = 32; off > 0; off >>= 1)
        v += __shfl_xor(v, off, 64);
    return v;
}

__global__ __launch_bounds__(256) void k_score(
    const int* __restrict__ r, const float* __restrict__ rel_w,
    const float* __restrict__ hp_raw, const float* __restrict__ tp_raw,
    float* __restrict__ out, int B)
{
    const int w    = threadIdx.x >> 6;
    const int lane = threadIdx.x & 63;
    const int b    = blockIdx.x * 4 + w;
    if (b >= B) return;

    const int   ri   = r[b];
    const int   mi   = (ri >= N_REL) ? ri - N_REL : ri;
    const float sign = (ri >= N_REL) ? -1.0f : 1.0f;

    const float2 hp = ((const float2*)(hp_raw + (size_t)b * DIM))[lane];
    const float2 tp = ((const float2*)(tp_raw + (size_t)b * DIM))[lane];
    const float2 rv = ((const float2*)(rel_w  + (size_t)mi * DIM))[lane];

    const float hs = waveSum(hp.x * hp.x + hp.y * hp.y);
    const float ts = waveSum(tp.x * tp.x + tp.y * tp.y);
    const float rs = waveSum(rv.x * rv.x + rv.y * rv.y);

    const float hinv = 1.0f / fmaxf(sqrtf(hs), EPS);
    const float tinv = 1.0f / fmaxf(sqrtf(ts), EPS);
    const float rinv = sign / fmaxf(sqrtf(rs), EPS);

    const float dx = hp.x * hinv + rv.x * rinv - tp.x * tinv;
    const float dy = hp.y * hinv + rv.y * rinv - tp.y * tinv;
    const float ds = waveSum(dx * dx + dy * dy);

    if (lane == 0) out[b] = GAMMA - sqrtf(ds);
}

// ---------------- launch ----------------

extern "C" void kernel_launch(void* const* d_in, const int* in_sizes, int n_in,
                              void* d_out, int out_size, void* d_ws, size_t ws_size,
                              hipStream_t stream) {
    const int*   h     = (const int*)d_in[0];
    const int*   r     = (const int*)d_in[1];
    const int*   t     = (const int*)d_in[2];
    const float* ent_w = (const float*)d_in[3];
    const float* rel_w = (const float*)d_in[4];
    const float* mat_w = (const float*)d_in[5];
    float*       out   = (float*)d_out;
    const int B = in_sizes[0];   // 16384

    int* counts  = (int*)d_ws;           // [512]
    int* offsets = counts + 512;         // [512]
    int* cursor  = counts + 1024;        // [512]
    int* order   = counts + 1536;        // [B]
    float* hp_raw = (float*)((char*)d_ws + (128 << 10));          // [B,128]
    float* tp_raw = hp_raw + (size_t)B * DIM;                     // [B,128]

    k_zero   <<<1, 512, 0, stream>>>(counts);
    k_hist   <<<(B + 255) / 256, 256, 0, stream>>>(r, counts, B);
    k_scan   <<<1, 512, 0, stream>>>(counts, offsets, cursor);
    k_scatter<<<(B + 255) / 256, 256, 0, stream>>>(r, cursor, order, B);
    k_matvec <<<N_REL, 256, 0, stream>>>(order, offsets, counts, h, t,
                                         ent_w, mat_w, hp_raw, tp_raw);
    k_score  <<<(B + 3) / 4, 256, 0, stream>>>(r, rel_w, hp_raw, tp_raw, out, B);
}